// Round 1
// baseline (984.049 us; speedup 1.0000x reference)
//
#include <hip/hip_runtime.h>

// Scatter_40656160424517: y = x @ W^T + b  (x:[N,64] fp32, W:[64,64], b:[64])
// out = segment_sum(y, idx, 262144)  -> [262144, 64] fp32
//
// Strategy (round 1 baseline):
//   - bf16 MFMA (16x16x32) for the per-row linear transform; W held entirely
//     in registers as B-fragments (loaded once per wave, L1-resident).
//   - fp32 global atomics for the scatter (134M atomics — this round measures
//     whether the atomic pipe is the bottleneck).
//   - d_out zeroed via hipMemsetAsync (harness poisons it with 0xAA).

typedef short  short8  __attribute__((ext_vector_type(8)));
typedef float  floatx4 __attribute__((ext_vector_type(4)));

// fp32 -> bf16 round-to-nearest-even (bit trick; inputs are finite gaussians)
__device__ inline short f2bf(float f) {
    unsigned u = __builtin_bit_cast(unsigned, f);
    u += 0x7fffu + ((u >> 16) & 1u);
    return (short)(u >> 16);
}

__device__ inline short8 cvt8v(float4 a, float4 b) {
    short8 r;
    r[0] = f2bf(a.x); r[1] = f2bf(a.y); r[2] = f2bf(a.z); r[3] = f2bf(a.w);
    r[4] = f2bf(b.x); r[5] = f2bf(b.y); r[6] = f2bf(b.z); r[7] = f2bf(b.w);
    return r;
}

__global__ __launch_bounds__(256) void scatter_linear_kernel(
    const float* __restrict__ x,     // [nrows, 64]
    const float* __restrict__ w,     // [64, 64] row-major [out_ch][in_ch]
    const float* __restrict__ bias,  // [64]
    const int*   __restrict__ idx,   // [nrows]
    float*       __restrict__ out,   // [num_seg, 64], pre-zeroed
    int nchunks)                     // nrows / 64
{
    const int lane = threadIdx.x & 63;
    const int wave = threadIdx.x >> 6;
    const int nl   = lane & 15;   // n (out-ch low) for B/C; m (row) for A
    const int q    = lane >> 4;   // quad: k-chunk selector for A/B; row-group for C

    // B fragments: B[k][n] = W[n][k].  bf[t][h] covers out-ch tile t (n = t*16+nl),
    // k in [q*8 + h*32, +8).  4 tiles x 2 k-halves x 8 bf16 = 32 VGPRs.
    short8 bf[4][2];
    float  bv[4];
#pragma unroll
    for (int t = 0; t < 4; ++t) {
        const float* wp = w + (t * 16 + nl) * 64 + q * 8;
        const float4* wp4a = (const float4*)wp;
        const float4* wp4b = (const float4*)(wp + 32);
        bf[t][0] = cvt8v(wp4a[0], wp4a[1]);
        bf[t][1] = cvt8v(wp4b[0], wp4b[1]);
        bv[t] = bias[t * 16 + nl];
    }

    // Grid-stride over 64-row chunks; each wave owns 16 rows of its chunk.
    for (long c = blockIdx.x; c < nchunks; c += gridDim.x) {
        const long base = c * 64 + wave * 16;

        // A fragments: A[m=nl][k = q*8 + h*32 + j] — 8 contiguous fp32 per frag.
        const float*  xp   = x + (base + nl) * 64 + q * 8;
        const float4* xp4a = (const float4*)xp;
        const float4* xp4b = (const float4*)(xp + 32);
        short8 af0 = cvt8v(xp4a[0], xp4a[1]);
        short8 af1 = cvt8v(xp4b[0], xp4b[1]);

        floatx4 acc[4];
#pragma unroll
        for (int t = 0; t < 4; ++t) {
            floatx4 z = {0.f, 0.f, 0.f, 0.f};
            acc[t] = __builtin_amdgcn_mfma_f32_16x16x32_bf16(af0, bf[t][0], z, 0, 0, 0);
            acc[t] = __builtin_amdgcn_mfma_f32_16x16x32_bf16(af1, bf[t][1], acc[t], 0, 0, 0);
        }

        // C/D: lane holds rows q*4+r (r=0..3), col t*16+nl.  Scatter-add.
#pragma unroll
        for (int r = 0; r < 4; ++r) {
            const long row = base + q * 4 + r;
            const int  s   = idx[row];
            float* op = out + (long)s * 64 + nl;
#pragma unroll
            for (int t = 0; t < 4; ++t)
                atomicAdd(op + t * 16, acc[t][r] + bv[t]);
        }
    }
}

extern "C" void kernel_launch(void* const* d_in, const int* in_sizes, int n_in,
                              void* d_out, int out_size, void* d_ws, size_t ws_size,
                              hipStream_t stream) {
    const float* x    = (const float*)d_in[0];
    const float* w    = (const float*)d_in[1];
    const float* bias = (const float*)d_in[2];
    const int*   idx  = (const int*)d_in[3];
    float*       out  = (float*)d_out;

    const int nrows   = in_sizes[0] / 64;   // 2097152
    const int nchunks = nrows / 64;         // 32768 (N divisible by 64 in this problem)

    // Harness poisons d_out with 0xAA before every timed call — zero it first.
    hipMemsetAsync(d_out, 0, (size_t)out_size * sizeof(float), stream);

    dim3 grid(8192), block(256);
    hipLaunchKernelGGL(scatter_linear_kernel, grid, block, 0, stream,
                       x, w, bias, idx, out, nchunks);
}